// Round 1
// baseline (304.562 us; speedup 1.0000x reference)
//
#include <hip/hip_runtime.h>

// Performer linear attention, fp32 baseline.
// B=4,H=16 -> BH=64 heads; N=4096; D=E=64.
// phaseA: partial context[d][e] = sum_n k[n][d]*v[n][e], partial ksum[d]
// phaseB: reduce partials over chunks
// phaseC: out[n][e] = (sum_d q[n][d]*ctx[d][e]) / (sum_d q[n][d]*ksum[d])

namespace {

constexpr int kBH  = 64;
constexpr int kN   = 4096;
constexpr int kD   = 64;
constexpr int kE   = 64;
constexpr int kSub = 64;   // rows per LDS sub-tile in phaseA

__global__ __launch_bounds__(256) void fa_phaseA(
    const float* __restrict__ k, const float* __restrict__ v,
    float* __restrict__ ctxp, float* __restrict__ ksump, int nc)
{
  const int bid = blockIdx.x;
  const int bh = bid / nc;
  const int chunk = bid - bh * nc;
  const int chunkLen = kN / nc;
  const float* kbase = k + ((size_t)bh * kN + (size_t)chunk * chunkLen) * kD;
  const float* vbase = v + ((size_t)bh * kN + (size_t)chunk * chunkLen) * kE;

  __shared__ float sk[kSub][kD];
  __shared__ float sv[kSub][kE];

  const int tid = threadIdx.x;
  const int d0 = (tid >> 4) * 4;   // 16 d-groups
  const int e0 = (tid & 15) * 4;   // 16 e-groups

  float acc[4][4] = {};
  float ks[4] = {};

  const int nsub = chunkLen / kSub;
  for (int s = 0; s < nsub; ++s) {
    const float4* ksrc = (const float4*)(kbase + (size_t)s * kSub * kD);
    const float4* vsrc = (const float4*)(vbase + (size_t)s * kSub * kE);
    __syncthreads();  // protect previous sub-tile's LDS reads
    float4* kdst = (float4*)(&sk[0][0]);
    float4* vdst = (float4*)(&sv[0][0]);
    #pragma unroll
    for (int i = 0; i < (kSub * kD / 4) / 256; ++i) {
      kdst[tid + i * 256] = ksrc[tid + i * 256];
      vdst[tid + i * 256] = vsrc[tid + i * 256];
    }
    __syncthreads();
    #pragma unroll 8
    for (int n = 0; n < kSub; ++n) {
      const float4 kk = *(const float4*)(&sk[n][d0]);  // 4 addrs/wave, distinct bank quads
      const float4 vv = *(const float4*)(&sv[n][e0]);  // 16 addrs, 2-way (free)
      const float kr[4] = {kk.x, kk.y, kk.z, kk.w};
      const float vr[4] = {vv.x, vv.y, vv.z, vv.w};
      #pragma unroll
      for (int i = 0; i < 4; ++i) {
        ks[i] += kr[i];
        #pragma unroll
        for (int j = 0; j < 4; ++j) acc[i][j] += kr[i] * vr[j];
      }
    }
  }

  float* cdst = ctxp + (size_t)bid * kD * kE;  // bid == bh*nc + chunk
  #pragma unroll
  for (int i = 0; i < 4; ++i) {
    *(float4*)(&cdst[(d0 + i) * kE + e0]) =
        make_float4(acc[i][0], acc[i][1], acc[i][2], acc[i][3]);
  }
  if (e0 == 0) {
    float* kd = ksump + (size_t)bid * kD;
    #pragma unroll
    for (int i = 0; i < 4; ++i) kd[d0 + i] = ks[i];
  }
}

__global__ __launch_bounds__(256) void fa_phaseB(
    const float* __restrict__ ctxp, const float* __restrict__ ksump,
    float* __restrict__ ctx, float* __restrict__ ksum, int nc)
{
  const int bh = blockIdx.x;
  const int tid = threadIdx.x;
  for (int i = tid; i < kD * kE; i += 256) {
    float s = 0.f;
    for (int c = 0; c < nc; ++c) s += ctxp[((size_t)bh * nc + c) * kD * kE + i];
    ctx[(size_t)bh * kD * kE + i] = s;
  }
  if (tid < kD) {
    float s = 0.f;
    for (int c = 0; c < nc; ++c) s += ksump[((size_t)bh * nc + c) * kD + tid];
    ksum[(size_t)bh * kD + tid] = s;
  }
}

__global__ __launch_bounds__(256) void fa_phaseC(
    const float* __restrict__ q, const float* __restrict__ ctx,
    const float* __restrict__ ksum, float* __restrict__ out)
{
  const int ntiles = kN / 64;
  const int bid = blockIdx.x;
  const int bh = bid / ntiles;
  const int tile = bid - bh * ntiles;
  const float* qbase = q + ((size_t)bh * kN + (size_t)tile * 64) * kD;
  float* obase = out + ((size_t)bh * kN + (size_t)tile * 64) * kE;

  __shared__ float sq[64][kD + 4];   // pad 4: keeps float4 alignment, 2-way max on reads
  __shared__ float sctx[kD][kE];
  __shared__ float sks[kD];

  const int tid = threadIdx.x;
  {
    const float4* qsrc = (const float4*)qbase;
    #pragma unroll
    for (int i = 0; i < 4; ++i) {
      const int t = tid + i * 256;
      const int n = t >> 4;
      const int d = (t & 15) * 4;
      *(float4*)(&sq[n][d]) = qsrc[t];
    }
    const float4* csrc = (const float4*)(ctx + (size_t)bh * kD * kE);
    float4* cdst = (float4*)(&sctx[0][0]);
    #pragma unroll
    for (int i = 0; i < 4; ++i) cdst[tid + i * 256] = csrc[tid + i * 256];
    if (tid < kD) sks[tid] = ksum[(size_t)bh * kD + tid];
  }
  __syncthreads();

  const int n0 = (tid >> 4) * 4;
  const int e0 = (tid & 15) * 4;
  float acc[4][4] = {};
  float den[4] = {};

  #pragma unroll 4
  for (int dq = 0; dq < kD; dq += 4) {
    float4 qv[4];
    #pragma unroll
    for (int i = 0; i < 4; ++i) qv[i] = *(const float4*)(&sq[n0 + i][dq]);
    float4 cv[4];
    #pragma unroll
    for (int u = 0; u < 4; ++u) cv[u] = *(const float4*)(&sctx[dq + u][e0]);
    const float4 kv = *(const float4*)(&sks[dq]);
    const float kr[4] = {kv.x, kv.y, kv.z, kv.w};
    #pragma unroll
    for (int i = 0; i < 4; ++i) {
      const float qr[4] = {qv[i].x, qv[i].y, qv[i].z, qv[i].w};
      #pragma unroll
      for (int u = 0; u < 4; ++u) {
        den[i] += qr[u] * kr[u];
        const float cu[4] = {cv[u].x, cv[u].y, cv[u].z, cv[u].w};
        #pragma unroll
        for (int j = 0; j < 4; ++j) acc[i][j] += qr[u] * cu[j];
      }
    }
  }

  #pragma unroll
  for (int i = 0; i < 4; ++i) {
    const float inv = 1.0f / den[i];
    *(float4*)(&obase[(size_t)(n0 + i) * kE + e0]) =
        make_float4(acc[i][0] * inv, acc[i][1] * inv, acc[i][2] * inv, acc[i][3] * inv);
  }
}

}  // namespace

extern "C" void kernel_launch(void* const* d_in, const int* in_sizes, int n_in,
                              void* d_out, int out_size, void* d_ws, size_t ws_size,
                              hipStream_t stream) {
  const float* q = (const float*)d_in[0];
  const float* k = (const float*)d_in[1];
  const float* v = (const float*)d_in[2];
  float* out = (float*)d_out;

  // scratch: partials [BH][nc][D*E + D] + reduced [BH][D*E + D]
  int nc = 16;
  auto need = [](int c) {
    return (size_t)(kBH * (size_t)c * (kD * kE + kD) + (size_t)kBH * (kD * kE + kD)) *
           sizeof(float);
  };
  while (nc > 1 && need(nc) > ws_size) nc >>= 1;

  float* ctxp  = (float*)d_ws;                               // [BH][nc][D][E]
  float* ksump = ctxp + (size_t)kBH * nc * kD * kE;          // [BH][nc][D]
  float* ctx   = ksump + (size_t)kBH * nc * kD;              // [BH][D][E]
  float* ksum  = ctx + (size_t)kBH * kD * kE;                // [BH][D]

  fa_phaseA<<<dim3(kBH * nc), dim3(256), 0, stream>>>(k, v, ctxp, ksump, nc);
  fa_phaseB<<<dim3(kBH), dim3(256), 0, stream>>>(ctxp, ksump, ctx, ksum, nc);
  fa_phaseC<<<dim3(kBH * (kN / 64)), dim3(256), 0, stream>>>(q, ctx, ksum, out);
}

// Round 2
// 262.097 us; speedup vs baseline: 1.1620x; 1.1620x over previous
//
#include <hip/hip_runtime.h>

// Performer linear attention, fp32, pipelined.
// B=4,H=16 -> BH=64 heads; N=4096; D=E=64.
// phaseA: partial context[d][e] = sum_n k[n][d]*v[n][e], partial ksum[d]
//         (double-buffered LDS via global_load_lds async DMA)
// phaseB: reduce partials over chunks (1 thread / output float4)
// phaseC: out[n][e] = (sum_d q[n][d]*ctx[d][e]) / (sum_d q[n][d]*ksum[d])
//         (ctx in LDS once; q streamed from global w/ wave broadcast)

namespace {

constexpr int kBH   = 64;
constexpr int kN    = 4096;
constexpr int kD    = 64;
constexpr int kE    = 64;
constexpr int kSubA = 32;   // rows per LDS sub-tile in phaseA

__device__ __forceinline__ void gload_lds16(const float* g, float* l) {
  __builtin_amdgcn_global_load_lds(
      (const __attribute__((address_space(1))) void*)g,
      (__attribute__((address_space(3))) void*)l,
      16, 0, 0);
}

__global__ __launch_bounds__(256) void fa_phaseA(
    const float* __restrict__ k, const float* __restrict__ v,
    float* __restrict__ ctxp, float* __restrict__ ksump, int nc)
{
  const int bid = blockIdx.x;
  const int bh = bid / nc;
  const int chunk = bid - bh * nc;
  const int chunkLen = kN / nc;
  const float* kbase = k + ((size_t)bh * kN + (size_t)chunk * chunkLen) * kD;
  const float* vbase = v + ((size_t)bh * kN + (size_t)chunk * chunkLen) * kE;

  __shared__ float sk[2][kSubA][kD];   // 2 x 8 KB
  __shared__ float sv[2][kSubA][kE];   // 2 x 8 KB

  const int tid = threadIdx.x;
  const int d0 = (tid >> 4) * 4;   // 16 d-groups (4 distinct/wave -> bank-clean)
  const int e0 = (tid & 15) * 4;   // 16 e-groups (2-way on b128 = free)

  // stage tile s into buffer b: 512 float4 of k + 512 float4 of v,
  // lds dest = uniform base + tid*16B (lane-linear, required by global_load_lds)
  auto stage = [&](int s, int b) {
    const float* ks = kbase + (size_t)s * kSubA * kD;
    const float* vs = vbase + (size_t)s * kSubA * kE;
    float* kd = &sk[b][0][0];
    float* vd = &sv[b][0][0];
    gload_lds16(ks + tid * 4,            kd + tid * 4);
    gload_lds16(ks + (tid + 256) * 4,    kd + (tid + 256) * 4);
    gload_lds16(vs + tid * 4,            vd + tid * 4);
    gload_lds16(vs + (tid + 256) * 4,    vd + (tid + 256) * 4);
  };

  float acc[4][4] = {};
  float ks[4] = {};

  const int nsub = chunkLen / kSubA;
  int cur = 0;
  stage(0, 0);
  for (int s = 0; s < nsub; ++s) {
    __syncthreads();   // drains vmcnt(0): buf[cur] ready; prev reads of buf[cur^1] done
    if (s + 1 < nsub) stage(s + 1, cur ^ 1);
    #pragma unroll 8
    for (int n = 0; n < kSubA; ++n) {
      const float4 kk = *(const float4*)(&sk[cur][n][d0]);
      const float4 vv = *(const float4*)(&sv[cur][n][e0]);
      const float kr[4] = {kk.x, kk.y, kk.z, kk.w};
      const float vr[4] = {vv.x, vv.y, vv.z, vv.w};
      #pragma unroll
      for (int i = 0; i < 4; ++i) {
        ks[i] += kr[i];
        #pragma unroll
        for (int j = 0; j < 4; ++j) acc[i][j] += kr[i] * vr[j];
      }
    }
    cur ^= 1;
  }

  float* cdst = ctxp + (size_t)bid * kD * kE;   // bid == bh*nc + chunk
  #pragma unroll
  for (int i = 0; i < 4; ++i) {
    *(float4*)(&cdst[(d0 + i) * kE + e0]) =
        make_float4(acc[i][0], acc[i][1], acc[i][2], acc[i][3]);
  }
  if (e0 == 0) {
    float* kd = ksump + (size_t)bid * kD;
    #pragma unroll
    for (int i = 0; i < 4; ++i) kd[d0 + i] = ks[i];
  }
}

// grid: 256 blocks for ctx (64 heads x 1024 float4) + 4 blocks for ksum
__global__ __launch_bounds__(256) void fa_phaseB(
    const float* __restrict__ ctxp, const float* __restrict__ ksump,
    float* __restrict__ ctx, float* __restrict__ ksum, int nc)
{
  const int g = blockIdx.x * 256 + threadIdx.x;
  if (blockIdx.x < 256) {
    const int bh = g >> 10;
    const int i4 = g & 1023;
    const float4* src = (const float4*)ctxp + (size_t)bh * nc * 1024 + i4;
    float4 s = make_float4(0.f, 0.f, 0.f, 0.f);
    #pragma unroll 4
    for (int c = 0; c < nc; ++c) {
      const float4 t = src[(size_t)c * 1024];
      s.x += t.x; s.y += t.y; s.z += t.z; s.w += t.w;
    }
    ((float4*)ctx)[(size_t)bh * 1024 + i4] = s;
  } else {
    const int g2 = g - 256 * 256;          // [0, 1024)
    const int bh = g2 >> 4;
    const int i4 = g2 & 15;
    const float4* src = (const float4*)ksump + (size_t)bh * nc * 16 + i4;
    float4 s = make_float4(0.f, 0.f, 0.f, 0.f);
    #pragma unroll 4
    for (int c = 0; c < nc; ++c) {
      const float4 t = src[(size_t)c * 16];
      s.x += t.x; s.y += t.y; s.z += t.z; s.w += t.w;
    }
    ((float4*)ksum)[(size_t)bh * 16 + i4] = s;
  }
}

__global__ __launch_bounds__(256) void fa_phaseC(
    const float* __restrict__ q, const float* __restrict__ ctx,
    const float* __restrict__ ksum, float* __restrict__ out)
{
  const int bid = blockIdx.x;
  const int bh = bid >> 6;          // 64 row-tiles per head
  const int tile = bid & 63;
  const float* qbase = q + ((size_t)bh * kN + (size_t)tile * 64) * kD;
  float* obase = out + ((size_t)bh * kN + (size_t)tile * 64) * kE;

  __shared__ float sctx[kD][kE];    // 16 KB
  __shared__ float sks[kD];

  const int tid = threadIdx.x;
  {
    const float4* csrc = (const float4*)(ctx + (size_t)bh * kD * kE);
    float4* cdst = (float4*)(&sctx[0][0]);
    cdst[tid]       = csrc[tid];
    cdst[tid + 256] = csrc[tid + 256];
    cdst[tid + 512] = csrc[tid + 512];
    cdst[tid + 768] = csrc[tid + 768];
    if (tid < 16)
      ((float4*)sks)[tid] = ((const float4*)(ksum + (size_t)bh * kD))[tid];
  }
  __syncthreads();

  const int n0 = (tid >> 4) * 4;    // 16 lanes share each q row-group -> broadcast loads
  const int e0 = (tid & 15) * 4;
  float acc[4][4] = {};
  float den[4] = {};

  #pragma unroll 4
  for (int dq = 0; dq < kD; dq += 4) {
    float4 qv[4];
    #pragma unroll
    for (int i = 0; i < 4; ++i)
      qv[i] = *(const float4*)(qbase + (size_t)(n0 + i) * kD + dq);
    float4 cv[4];
    #pragma unroll
    for (int u = 0; u < 4; ++u) cv[u] = *(const float4*)(&sctx[dq + u][e0]);
    const float4 kv = *(const float4*)(&sks[dq]);
    const float kr[4] = {kv.x, kv.y, kv.z, kv.w};
    #pragma unroll
    for (int i = 0; i < 4; ++i) {
      const float qr[4] = {qv[i].x, qv[i].y, qv[i].z, qv[i].w};
      #pragma unroll
      for (int u = 0; u < 4; ++u) {
        den[i] += qr[u] * kr[u];
        const float cu[4] = {cv[u].x, cv[u].y, cv[u].z, cv[u].w};
        #pragma unroll
        for (int j = 0; j < 4; ++j) acc[i][j] += qr[u] * cu[j];
      }
    }
  }

  #pragma unroll
  for (int i = 0; i < 4; ++i) {
    const float inv = 1.0f / den[i];
    *(float4*)(&obase[(size_t)(n0 + i) * kE + e0]) =
        make_float4(acc[i][0] * inv, acc[i][1] * inv, acc[i][2] * inv, acc[i][3] * inv);
  }
}

}  // namespace

extern "C" void kernel_launch(void* const* d_in, const int* in_sizes, int n_in,
                              void* d_out, int out_size, void* d_ws, size_t ws_size,
                              hipStream_t stream) {
  const float* q = (const float*)d_in[0];
  const float* k = (const float*)d_in[1];
  const float* v = (const float*)d_in[2];
  float* out = (float*)d_out;

  // scratch: partials [BH][nc][D*E + D] + reduced [BH][D*E + D]
  int nc = 16;
  auto need = [](int c) {
    return (size_t)(kBH * (size_t)c * (kD * kE + kD) + (size_t)kBH * (kD * kE + kD)) *
           sizeof(float);
  };
  while (nc > 1 && need(nc) > ws_size) nc >>= 1;

  float* ctxp  = (float*)d_ws;                               // [BH][nc][D][E]
  float* ksump = ctxp + (size_t)kBH * nc * kD * kE;          // [BH][nc][D]
  float* ctx   = ksump + (size_t)kBH * nc * kD;              // [BH][D][E]
  float* ksum  = ctx + (size_t)kBH * kD * kE;                // [BH][D]

  fa_phaseA<<<dim3(kBH * nc), dim3(256), 0, stream>>>(k, v, ctxp, ksump, nc);
  fa_phaseB<<<dim3(260), dim3(256), 0, stream>>>(ctxp, ksump, ctx, ksum, nc);
  fa_phaseC<<<dim3(kBH * (kN / 64)), dim3(256), 0, stream>>>(q, ctx, ksum, out);
}

// Round 4
// 239.319 us; speedup vs baseline: 1.2726x; 1.0952x over previous
//
#include <hip/hip_runtime.h>

// Performer linear attention, bf16-MFMA version. (Round-3 resubmit — the
// previous bench died to a container-acquisition failure, not a kernel error.)
// B=4,H=16 -> BH=64 heads; N=4096; D=E=64.
// phaseA: partial ctx[d][e] = sum_n k[n][d]*v[n][e] via mfma_f32_16x16x32_bf16
//         (fragments gathered directly from global; no LDS), ksum in fp32.
// phaseB: reduce partials over chunks; emit ctxT[e][d] bf16 + ksum bf16.
// phaseC: out[n][e] = (q·ctx)[n][e] / (q·ksum)[n] via MFMA; den = extra MFMA
//         with B = [ksum | 0]; no LDS at all.

namespace {

constexpr int kBH = 64;
constexpr int kN  = 4096;
constexpr int kD  = 64;
constexpr int kE  = 64;

using frag_ab = __attribute__((ext_vector_type(8))) short;  // 8 bf16
using frag_cd = __attribute__((ext_vector_type(4))) float;  // 4 fp32

__device__ __forceinline__ short f2bf(float f) {
  unsigned u = __float_as_uint(f);
  u += 0x7FFF + ((u >> 16) & 1);   // RNE
  return (short)(u >> 16);
}

// ---------------- phaseA ----------------
// grid: kBH*nc blocks x 256 thr (4 waves). Wave w owns d-tile w (rows 16w..16w+15).
// Each block covers K-chunk of kN/nc keys; 16x16x32 MFMA over et=0..3.
__global__ __launch_bounds__(256) void fa_phaseA(
    const float* __restrict__ k, const float* __restrict__ v,
    float* __restrict__ ctxp, float* __restrict__ ksump, int nc)
{
  const int bid = blockIdx.x;
  const int bh = bid / nc;
  const int chunk = bid - bh * nc;
  const int chunkLen = kN / nc;
  const float* kbase = k + ((size_t)bh * kN + (size_t)chunk * chunkLen) * kD;
  const float* vbase = v + ((size_t)bh * kN + (size_t)chunk * chunkLen) * kE;

  const int tid = threadIdx.x;
  const int w = tid >> 6;        // wave id == d-tile
  const int lane = tid & 63;
  const int r = lane & 15;       // A row / B col within 16-tile
  const int g = lane >> 4;       // k-octet selector

  frag_cd acc[4];
  #pragma unroll
  for (int et = 0; et < 4; ++et) acc[et] = frag_cd{0.f, 0.f, 0.f, 0.f};
  float ksp = 0.f;

  const int nsteps = chunkLen / 32;
  for (int s = 0; s < nsteps; ++s) {
    const int n0 = s * 32 + 8 * g;
    const float* pa = kbase + (size_t)n0 * kD + 16 * w + r;  // k[n][16w+r], n=n0..n0+7
    const float* pb = vbase + (size_t)n0 * kE + r;           // v[n][16et+r]

    // A fragment: k column gather (8 loads, imm offsets 0..1792B off one base)
    float ka[8];
    #pragma unroll
    for (int b = 0; b < 8; ++b) ka[b] = pa[b * 64];
    // B fragments: v column gathers
    float vb[4][8];
    #pragma unroll
    for (int et = 0; et < 4; ++et)
      #pragma unroll
      for (int b = 0; b < 8; ++b) vb[et][b] = pb[et * 16 + b * 64];

    frag_ab af;
    #pragma unroll
    for (int b = 0; b < 8; ++b) { af[b] = f2bf(ka[b]); ksp += ka[b]; }
    #pragma unroll
    for (int et = 0; et < 4; ++et) {
      frag_ab bf;
      #pragma unroll
      for (int b = 0; b < 8; ++b) bf[b] = f2bf(vb[et][b]);
      acc[et] = __builtin_amdgcn_mfma_f32_16x16x32_bf16(af, bf, acc[et], 0, 0, 0);
    }
  }

  // ksum: lanes (r, r+16, r+32, r+48) hold partials for d = 16w+r
  ksp += __shfl_xor(ksp, 16);
  ksp += __shfl_xor(ksp, 32);
  if (lane < 16) ksump[(size_t)bid * kD + 16 * w + lane] = ksp;

  // ctx partial: D layout col=lane&15, row=(lane>>4)*4+reg
  float* cdst = ctxp + (size_t)bid * kD * kE;
  #pragma unroll
  for (int et = 0; et < 4; ++et)
    #pragma unroll
    for (int reg = 0; reg < 4; ++reg)
      cdst[(size_t)(16 * w + 4 * g + reg) * kE + 16 * et + r] = acc[et][reg];
}

// ---------------- phaseB ----------------
// blocks 0..255: ctx reduce + transpose + bf16 (4 outputs/thread)
// blocks 256..259: ksum reduce + bf16
__global__ __launch_bounds__(256) void fa_phaseB(
    const float* __restrict__ ctxp, const float* __restrict__ ksump,
    short* __restrict__ ctxT, short* __restrict__ ksumb, int nc)
{
  const int t = blockIdx.x * 256 + threadIdx.x;
  if (blockIdx.x < 256) {
    const int head = t >> 10;
    const int i = t & 1023;           // 1024 d-quads per head
    const int e = i >> 4;
    const int d0 = (i & 15) * 4;
    const float* src = ctxp + (size_t)head * nc * (kD * kE) + e;
    float s0 = 0.f, s1 = 0.f, s2 = 0.f, s3 = 0.f;
    for (int c = 0; c < nc; ++c) {
      const float* p = src + (size_t)c * (kD * kE);
      s0 += p[(d0 + 0) * kE]; s1 += p[(d0 + 1) * kE];
      s2 += p[(d0 + 2) * kE]; s3 += p[(d0 + 3) * kE];
    }
    short* dst = ctxT + (size_t)head * (kD * kE) + e * kD + d0;
    int lo = (unsigned short)f2bf(s0) | ((unsigned)(unsigned short)f2bf(s1) << 16);
    int hi = (unsigned short)f2bf(s2) | ((unsigned)(unsigned short)f2bf(s3) << 16);
    *(int2*)dst = make_int2(lo, hi);
  } else {
    const int t2 = t - 256 * 256;     // [0, 1024)
    if (t2 >= kBH * 16) return;
    const int head = t2 >> 4;
    const int d0 = (t2 & 15) * 4;
    const float* src = ksump + (size_t)head * nc * kD + d0;
    float s[4] = {0.f, 0.f, 0.f, 0.f};
    for (int c = 0; c < nc; ++c) {
      const float* p = src + (size_t)c * kD;
      s[0] += p[0]; s[1] += p[1]; s[2] += p[2]; s[3] += p[3];
    }
    short* dst = ksumb + (size_t)head * kD + d0;
    int lo = (unsigned short)f2bf(s[0]) | ((unsigned)(unsigned short)f2bf(s[1]) << 16);
    int hi = (unsigned short)f2bf(s[2]) | ((unsigned)(unsigned short)f2bf(s[3]) << 16);
    *(int2*)dst = make_int2(lo, hi);
  }
}

// ---------------- phaseC ----------------
// grid: kBH*32 blocks x 256 thr. Block = 128 q-rows; wave = 32 rows (rt=0,1).
// K=64 -> ks=0,1. et=0..3. Extra MFMA per (rt,ks) for denominator.
__global__ __launch_bounds__(256) void fa_phaseC(
    const float* __restrict__ q, const short* __restrict__ ctxT,
    const short* __restrict__ ksumb, float* __restrict__ out)
{
  const int bid = blockIdx.x;
  const int bh = bid >> 5;
  const int tile = bid & 31;
  const int tid = threadIdx.x;
  const int w = tid >> 6;
  const int lane = tid & 63;
  const int r = lane & 15;
  const int g = lane >> 4;
  const int rowb = tile * 128 + w * 32;

  const float* qb = q + ((size_t)bh * kN + rowb) * kD;
  const short* cb = ctxT + (size_t)bh * kD * kE;   // [e][d] bf16
  const short* kb = ksumb + (size_t)bh * kD;

  // B fragments (ctxT rows are contiguous in d -> 16B vector loads, L2-hot)
  frag_ab B[4][2];
  #pragma unroll
  for (int et = 0; et < 4; ++et)
    #pragma unroll
    for (int ks = 0; ks < 2; ++ks)
      B[et][ks] = *(const frag_ab*)(cb + (size_t)(16 * et + r) * kD + 32 * ks + 8 * g);

  const frag_ab zero8 = frag_ab{0, 0, 0, 0, 0, 0, 0, 0};
  frag_ab Bk[2];
  #pragma unroll
  for (int ks = 0; ks < 2; ++ks) {
    frag_ab t = *(const frag_ab*)(kb + 32 * ks + 8 * g);
    Bk[ks] = (r == 0) ? t : zero8;   // col 0 = ksum, cols 1..15 = 0
  }

  // A fragments: q rows direct from global, fp32 -> bf16
  frag_ab A[2][2];
  #pragma unroll
  for (int rt = 0; rt < 2; ++rt)
    #pragma unroll
    for (int ks = 0; ks < 2; ++ks) {
      const float* pq = qb + (size_t)(16 * rt + r) * kD + 32 * ks + 8 * g;
      const float4 lo = *(const float4*)pq;
      const float4 hi = *(const float4*)(pq + 4);
      frag_ab a;
      a[0] = f2bf(lo.x); a[1] = f2bf(lo.y); a[2] = f2bf(lo.z); a[3] = f2bf(lo.w);
      a[4] = f2bf(hi.x); a[5] = f2bf(hi.y); a[6] = f2bf(hi.z); a[7] = f2bf(hi.w);
      A[rt][ks] = a;
    }

  frag_cd acc[2][4];
  frag_cd dacc[2];
  #pragma unroll
  for (int rt = 0; rt < 2; ++rt) {
    dacc[rt] = frag_cd{0.f, 0.f, 0.f, 0.f};
    #pragma unroll
    for (int et = 0; et < 4; ++et) acc[rt][et] = frag_cd{0.f, 0.f, 0.f, 0.f};
  }

  #pragma unroll
  for (int rt = 0; rt < 2; ++rt)
    #pragma unroll
    for (int ks = 0; ks < 2; ++ks) {
      #pragma unroll
      for (int et = 0; et < 4; ++et)
        acc[rt][et] =
            __builtin_amdgcn_mfma_f32_16x16x32_bf16(A[rt][ks], B[et][ks], acc[rt][et], 0, 0, 0);
      dacc[rt] =
          __builtin_amdgcn_mfma_f32_16x16x32_bf16(A[rt][ks], Bk[ks], dacc[rt], 0, 0, 0);
    }

  float* ob = out + ((size_t)bh * kN + rowb) * kE;
  #pragma unroll
  for (int rt = 0; rt < 2; ++rt) {
    float inv[4];
    #pragma unroll
    for (int reg = 0; reg < 4; ++reg) {
      const float dv = __shfl(dacc[rt][reg], lane & 48);  // den from col-0 lane of my group
      inv[reg] = 1.0f / dv;
    }
    #pragma unroll
    for (int et = 0; et < 4; ++et)
      #pragma unroll
      for (int reg = 0; reg < 4; ++reg)
        ob[(size_t)(16 * rt + 4 * g + reg) * kE + 16 * et + r] = acc[rt][et][reg] * inv[reg];
  }
}

}  // namespace

extern "C" void kernel_launch(void* const* d_in, const int* in_sizes, int n_in,
                              void* d_out, int out_size, void* d_ws, size_t ws_size,
                              hipStream_t stream) {
  const float* q = (const float*)d_in[0];
  const float* k = (const float*)d_in[1];
  const float* v = (const float*)d_in[2];
  float* out = (float*)d_out;

  int nc = 16;
  auto need = [](int c) {
    return (size_t)(kBH * (size_t)c * (kD * kE + kD)) * sizeof(float) +
           (size_t)(kBH * (kD * kE + kD)) * sizeof(short);
  };
  while (nc > 1 && need(nc) > ws_size) nc >>= 1;

  float* ctxp  = (float*)d_ws;                        // [BH][nc][D][E] fp32
  float* ksump = ctxp + (size_t)kBH * nc * kD * kE;   // [BH][nc][D] fp32
  short* ctxT  = (short*)(ksump + (size_t)kBH * nc * kD);  // [BH][E][D] bf16
  short* ksumb = ctxT + (size_t)kBH * kD * kE;        // [BH][D] bf16

  fa_phaseA<<<dim3(kBH * nc), dim3(256), 0, stream>>>(k, v, ctxp, ksump, nc);
  fa_phaseB<<<dim3(260), dim3(256), 0, stream>>>(ctxp, ksump, ctxT, ksumb, nc);
  fa_phaseC<<<dim3(kBH * 32), dim3(256), 0, stream>>>(q, ctxT, ksumb, out);
}

// Round 5
// 234.430 us; speedup vs baseline: 1.2992x; 1.0209x over previous
//
#include <hip/hip_runtime.h>

// Performer linear attention, bf16-MFMA, round 5.
// B=4,H=16 -> BH=64 heads; N=4096; D=E=64.
// phaseA v2: reg-staged coalesced loads -> bf16 convert -> TRANSPOSED LDS
//            (kT[d][n], vT[e][n], row stride 40 el = 80 B) -> ds_read_b128
//            fragments -> mfma_f32_16x16x32_bf16. ksum via ones-MFMA.
//            Double-buffered, loads issued early (async-split).
// phaseB: reduce partials over chunks; emit ctxT[e][d] bf16 + ksum bf16.
// phaseC: out[n][e] = (q.ctx)[n][e] / (q.ksum)[n] via MFMA; den = extra MFMA.

namespace {

constexpr int kBH = 64;
constexpr int kN  = 4096;
constexpr int kD  = 64;
constexpr int kE  = 64;
constexpr int kLS = 40;   // LDS row stride in bf16 elements (80 B: 16B-aligned, anti-banking)

using frag_ab = __attribute__((ext_vector_type(8))) short;  // 8 bf16
using frag_cd = __attribute__((ext_vector_type(4))) float;  // 4 fp32

__device__ __forceinline__ short f2bf(float f) {
  unsigned u = __float_as_uint(f);
  u += 0x7FFF + ((u >> 16) & 1);   // RNE
  return (short)(u >> 16);
}
__device__ __forceinline__ int pack2(float a, float b) {
  return (int)(unsigned short)f2bf(a) | ((int)(unsigned short)f2bf(b) << 16);
}

// ---------------- phaseA ----------------
// grid: kBH*nc blocks x 256 thr (4 waves). Wave w owns d-tile w.
// Per 32-key step: stage k/v 32x64 fp32 -> bf16 transposed LDS; 6 MFMAs.
__global__ __launch_bounds__(256) void fa_phaseA(
    const float* __restrict__ k, const float* __restrict__ v,
    float* __restrict__ ctxp, float* __restrict__ ksump, int nc)
{
  const int bid = blockIdx.x;
  const int bh = bid / nc;
  const int chunk = bid - bh * nc;
  const int chunkLen = kN / nc;
  const float* kbase = k + ((size_t)bh * kN + (size_t)chunk * chunkLen) * kD;
  const float* vbase = v + ((size_t)bh * kN + (size_t)chunk * chunkLen) * kE;

  const int tid = threadIdx.x;
  const int w = tid >> 6;        // wave id == d-tile
  const int lane = tid & 63;
  const int r = lane & 15;       // A row / B col within 16-tile
  const int g = lane >> 4;       // k-octet selector
  const int u = tid & 15;        // stage: d-quad (d = 4u..4u+3)
  const int p = tid >> 4;        // stage: n-pair  (n = 2p, 2p+1)

  __shared__ __align__(16) short skT[2][64 * kLS];   // kT[d][n] bf16, 2x5 KB
  __shared__ __align__(16) short svT[2][64 * kLS];   // vT[e][n] bf16

  frag_cd acc[4];
  #pragma unroll
  for (int et = 0; et < 4; ++et) acc[et] = frag_cd{0.f, 0.f, 0.f, 0.f};
  frag_cd dacc = frag_cd{0.f, 0.f, 0.f, 0.f};
  frag_ab ones;
  #pragma unroll
  for (int i = 0; i < 8; ++i) ones[i] = (short)0x3F80;   // bf16 1.0

  float4 rk0, rk1, rv0, rv1;   // staged rows: k[2p], k[2p+1], v[2p], v[2p+1] (4 floats @ d=4u)
  auto loadrows = [&](int s) {
    const float* kp = kbase + ((size_t)s * 32 + 2 * p) * kD + 4 * u;
    const float* vp = vbase + ((size_t)s * 32 + 2 * p) * kE + 4 * u;
    rk0 = *(const float4*)kp;        rk1 = *(const float4*)(kp + kD);
    rv0 = *(const float4*)vp;        rv1 = *(const float4*)(vp + kE);
  };
  auto writebuf = [&](int b) {
    short* kt = &skT[b][0];
    short* vt = &svT[b][0];
    const float k0[4] = {rk0.x, rk0.y, rk0.z, rk0.w};
    const float k1[4] = {rk1.x, rk1.y, rk1.z, rk1.w};
    const float v0[4] = {rv0.x, rv0.y, rv0.z, rv0.w};
    const float v1[4] = {rv1.x, rv1.y, rv1.z, rv1.w};
    #pragma unroll
    for (int i = 0; i < 4; ++i) {
      *(int*)(kt + (4 * u + i) * kLS + 2 * p) = pack2(k0[i], k1[i]);
      *(int*)(vt + (4 * u + i) * kLS + 2 * p) = pack2(v0[i], v1[i]);
    }
  };

  const int nsub = chunkLen / 32;
  loadrows(0);
  writebuf(0);
  int cur = 0;
  for (int s = 0; s < nsub; ++s) {
    __syncthreads();   // buf[cur] writes visible; prior reads of buf[cur^1] retired
    if (s + 1 < nsub) loadrows(s + 1);   // issue early; vmcnt waited at writebuf below
    const short* kt = &skT[cur][0];
    const short* vt = &svT[cur][0];
    const frag_ab A  = *(const frag_ab*)(kt + (16 * w + r) * kLS + 8 * g);
    const frag_ab B0 = *(const frag_ab*)(vt + (r)           * kLS + 8 * g);
    const frag_ab B1 = *(const frag_ab*)(vt + (16 + r)      * kLS + 8 * g);
    const frag_ab B2 = *(const frag_ab*)(vt + (32 + r)      * kLS + 8 * g);
    const frag_ab B3 = *(const frag_ab*)(vt + (48 + r)      * kLS + 8 * g);
    acc[0] = __builtin_amdgcn_mfma_f32_16x16x32_bf16(A, B0, acc[0], 0, 0, 0);
    acc[1] = __builtin_amdgcn_mfma_f32_16x16x32_bf16(A, B1, acc[1], 0, 0, 0);
    acc[2] = __builtin_amdgcn_mfma_f32_16x16x32_bf16(A, B2, acc[2], 0, 0, 0);
    acc[3] = __builtin_amdgcn_mfma_f32_16x16x32_bf16(A, B3, acc[3], 0, 0, 0);
    dacc   = __builtin_amdgcn_mfma_f32_16x16x32_bf16(A, ones, dacc, 0, 0, 0);
    if (s + 1 < nsub) writebuf(cur ^ 1);
    cur ^= 1;
  }

  // ctx partial: D layout col=lane&15, row=4*(lane>>4)+reg
  float* cdst = ctxp + (size_t)bid * kD * kE;
  #pragma unroll
  for (int et = 0; et < 4; ++et)
    #pragma unroll
    for (int reg = 0; reg < 4; ++reg)
      cdst[(size_t)(16 * w + 4 * g + reg) * kE + 16 * et + r] = acc[et][reg];
  // ksum partial: every col of dacc equals ksum[row]; take col-0 lanes
  if (r == 0) {
    #pragma unroll
    for (int reg = 0; reg < 4; ++reg)
      ksump[(size_t)bid * kD + 16 * w + 4 * g + reg] = dacc[reg];
  }
}

// ---------------- phaseB ----------------
// blocks 0..255: ctx reduce + transpose + bf16 (4 outputs/thread)
// blocks 256..259: ksum reduce + bf16
__global__ __launch_bounds__(256) void fa_phaseB(
    const float* __restrict__ ctxp, const float* __restrict__ ksump,
    short* __restrict__ ctxT, short* __restrict__ ksumb, int nc)
{
  const int t = blockIdx.x * 256 + threadIdx.x;
  if (blockIdx.x < 256) {
    const int head = t >> 10;
    const int i = t & 1023;           // 1024 d-quads per head
    const int e = i >> 4;
    const int d0 = (i & 15) * 4;
    const float* src = ctxp + (size_t)head * nc * (kD * kE) + e;
    float s0 = 0.f, s1 = 0.f, s2 = 0.f, s3 = 0.f;
    for (int c = 0; c < nc; ++c) {
      const float* ptr = src + (size_t)c * (kD * kE);
      s0 += ptr[(d0 + 0) * kE]; s1 += ptr[(d0 + 1) * kE];
      s2 += ptr[(d0 + 2) * kE]; s3 += ptr[(d0 + 3) * kE];
    }
    short* dst = ctxT + (size_t)head * (kD * kE) + e * kD + d0;
    *(int2*)dst = make_int2(pack2(s0, s1), pack2(s2, s3));
  } else {
    const int t2 = t - 256 * 256;     // [0, 1024)
    if (t2 >= kBH * 16) return;
    const int head = t2 >> 4;
    const int d0 = (t2 & 15) * 4;
    const float* src = ksump + (size_t)head * nc * kD + d0;
    float s[4] = {0.f, 0.f, 0.f, 0.f};
    for (int c = 0; c < nc; ++c) {
      const float* ptr = src + (size_t)c * kD;
      s[0] += ptr[0]; s[1] += ptr[1]; s[2] += ptr[2]; s[3] += ptr[3];
    }
    short* dst = ksumb + (size_t)head * kD + d0;
    *(int2*)dst = make_int2(pack2(s[0], s[1]), pack2(s[2], s[3]));
  }
}

// ---------------- phaseC ----------------
// grid: kBH*32 blocks x 256 thr. Block = 128 q-rows; wave = 32 rows (rt=0,1).
__global__ __launch_bounds__(256) void fa_phaseC(
    const float* __restrict__ q, const short* __restrict__ ctxT,
    const short* __restrict__ ksumb, float* __restrict__ out)
{
  const int bid = blockIdx.x;
  const int bh = bid >> 5;
  const int tile = bid & 31;
  const int tid = threadIdx.x;
  const int w = tid >> 6;
  const int lane = tid & 63;
  const int r = lane & 15;
  const int g = lane >> 4;
  const int rowb = tile * 128 + w * 32;

  const float* qb = q + ((size_t)bh * kN + rowb) * kD;
  const short* cb = ctxT + (size_t)bh * kD * kE;   // [e][d] bf16
  const short* kb = ksumb + (size_t)bh * kD;

  frag_ab B[4][2];
  #pragma unroll
  for (int et = 0; et < 4; ++et)
    #pragma unroll
    for (int ks = 0; ks < 2; ++ks)
      B[et][ks] = *(const frag_ab*)(cb + (size_t)(16 * et + r) * kD + 32 * ks + 8 * g);

  const frag_ab zero8 = frag_ab{0, 0, 0, 0, 0, 0, 0, 0};
  frag_ab Bk[2];
  #pragma unroll
  for (int ks = 0; ks < 2; ++ks) {
    frag_ab t = *(const frag_ab*)(kb + 32 * ks + 8 * g);
    Bk[ks] = (r == 0) ? t : zero8;   // col 0 = ksum, cols 1..15 = 0
  }

  frag_ab A[2][2];
  #pragma unroll
  for (int rt = 0; rt < 2; ++rt)
    #pragma unroll
    for (int ks = 0; ks < 2; ++ks) {
      const float* pq = qb + (size_t)(16 * rt + r) * kD + 32 * ks + 8 * g;
      const float4 lo = *(const float4*)pq;
      const float4 hi = *(const float4*)(pq + 4);
      frag_ab a;
      a[0] = f2bf(lo.x); a[1] = f2bf(lo.y); a[2] = f2bf(lo.z); a[3] = f2bf(lo.w);
      a[4] = f2bf(hi.x); a[5] = f2bf(hi.y); a[6] = f2bf(hi.z); a[7] = f2bf(hi.w);
      A[rt][ks] = a;
    }

  frag_cd acc[2][4];
  frag_cd dacc[2];
  #pragma unroll
  for (int rt = 0; rt < 2; ++rt) {
    dacc[rt] = frag_cd{0.f, 0.f, 0.f, 0.f};
    #pragma unroll
    for (int et = 0; et < 4; ++et) acc[rt][et] = frag_cd{0.f, 0.f, 0.f, 0.f};
  }

  #pragma unroll
  for (int rt = 0; rt < 2; ++rt)
    #pragma unroll
    for (int ks = 0; ks < 2; ++ks) {
      #pragma unroll
      for (int et = 0; et < 4; ++et)
        acc[rt][et] =
            __builtin_amdgcn_mfma_f32_16x16x32_bf16(A[rt][ks], B[et][ks], acc[rt][et], 0, 0, 0);
      dacc[rt] =
          __builtin_amdgcn_mfma_f32_16x16x32_bf16(A[rt][ks], Bk[ks], dacc[rt], 0, 0, 0);
    }

  float* ob = out + ((size_t)bh * kN + rowb) * kE;
  #pragma unroll
  for (int rt = 0; rt < 2; ++rt) {
    float inv[4];
    #pragma unroll
    for (int reg = 0; reg < 4; ++reg) {
      const float dv = __shfl(dacc[rt][reg], lane & 48);
      inv[reg] = 1.0f / dv;
    }
    #pragma unroll
    for (int et = 0; et < 4; ++et)
      #pragma unroll
      for (int reg = 0; reg < 4; ++reg)
        ob[(size_t)(16 * rt + 4 * g + reg) * kE + 16 * et + r] = acc[rt][et][reg] * inv[reg];
  }
}

}  // namespace

extern "C" void kernel_launch(void* const* d_in, const int* in_sizes, int n_in,
                              void* d_out, int out_size, void* d_ws, size_t ws_size,
                              hipStream_t stream) {
  const float* q = (const float*)d_in[0];
  const float* k = (const float*)d_in[1];
  const float* v = (const float*)d_in[2];
  float* out = (float*)d_out;

  int nc = 16;
  auto need = [](int c) {
    return (size_t)(kBH * (size_t)c * (kD * kE + kD)) * sizeof(float) +
           (size_t)(kBH * (kD * kE + kD)) * sizeof(short);
  };
  while (nc > 1 && need(nc) > ws_size) nc >>= 1;

  float* ctxp  = (float*)d_ws;                        // [BH][nc][D][E] fp32
  float* ksump = ctxp + (size_t)kBH * nc * kD * kE;   // [BH][nc][D] fp32
  short* ctxT  = (short*)(ksump + (size_t)kBH * nc * kD);  // [BH][E][D] bf16
  short* ksumb = ctxT + (size_t)kBH * kD * kE;        // [BH][D] bf16

  fa_phaseA<<<dim3(kBH * nc), dim3(256), 0, stream>>>(k, v, ctxp, ksump, nc);
  fa_phaseB<<<dim3(260), dim3(256), 0, stream>>>(ctxp, ksump, ctxT, ksumb, nc);
  fa_phaseC<<<dim3(kBH * 32), dim3(256), 0, stream>>>(q, ctxT, ksumb, out);
}